// Round 2
// baseline (422.733 us; speedup 1.0000x reference)
//
#include <hip/hip_runtime.h>
#include <math.h>

#define BB 4
#define LL 1024
#define DD 256
#define KK 64
#define NN (BB*LL)   // 4096 tokens

// ---------------------------------------------------------------------------
// Kernel A: per-token encoder. 16 tokens per block, 256 threads.
//   h  = gelu(x@W1+b1)            (exact gelu, erf)
//   cp = tanh(h@W2+b2)*pi
//   amp= softplus(x@Wa+ba)+0.1
//   phase = pos_phases[l] + cp
//   Pr = amp*cos(phase), Pim = amp*sin(phase)
//   V  = x@Wv+bv
// ---------------------------------------------------------------------------
__global__ __launch_bounds__(256)
void encode_kernel(const float* __restrict__ x, const float* __restrict__ pos,
                   const float* __restrict__ W1, const float* __restrict__ b1,
                   const float* __restrict__ W2, const float* __restrict__ b2,
                   const float* __restrict__ Wa, const float* __restrict__ ba,
                   const float* __restrict__ Wv, const float* __restrict__ bv,
                   float* __restrict__ Vout, float* __restrict__ Pr,
                   float* __restrict__ Pim)
{
    __shared__ float xs[16][DD];   // reads are wave-broadcast; no pad needed
    __shared__ float hs[16][DD];
    const int t = threadIdx.x;
    const int tok0 = blockIdx.x * 16;

    for (int i = t; i < 16*DD; i += 256)
        xs[i>>8][i&255] = x[(size_t)tok0*DD + i];
    __syncthreads();

    // D-wide outputs: thread t owns column t
    float acc1[16], acc2[16];
    #pragma unroll
    for (int r = 0; r < 16; r++){ acc1[r]=0.f; acc2[r]=0.f; }
    for (int j = 0; j < DD; j++){
        float w1 = W1[j*DD + t];        // coalesced across t
        float wv = Wv[j*DD + t];
        #pragma unroll
        for (int r = 0; r < 16; r++){
            float xv = xs[r][j];        // LDS broadcast
            acc1[r] += xv*w1;
            acc2[r] += xv*wv;
        }
    }
    float bb1 = b1[t], bbv = bv[t];
    #pragma unroll
    for (int r = 0; r < 16; r++){
        float hpre = acc1[r] + bb1;
        hs[r][t] = 0.5f*hpre*(1.0f + erff(hpre*0.70710678118f));  // exact gelu
        Vout[(size_t)(tok0+r)*DD + t] = acc2[r] + bbv;
    }
    __syncthreads();

    // K-wide outputs: wave w (=t>>6) handles rows 4w..4w+3, lane = k
    const int k  = t & 63;
    const int rg = t >> 6;
    float a2[4], aa[4];
    #pragma unroll
    for (int r = 0; r < 4; r++){ a2[r]=0.f; aa[r]=0.f; }
    for (int j = 0; j < DD; j++){
        float w2 = W2[j*KK + k];
        float wa = Wa[j*KK + k];
        #pragma unroll
        for (int r = 0; r < 4; r++){
            a2[r] += hs[rg*4+r][j]*w2;  // LDS broadcast (same row per wave)
            aa[r] += xs[rg*4+r][j]*wa;
        }
    }
    float bb2 = b2[k], bba = ba[k];
    const float PI_ = 3.14159265358979323846f;
    #pragma unroll
    for (int r = 0; r < 4; r++){
        int tok = tok0 + rg*4 + r;
        float cp = tanhf(a2[r] + bb2) * PI_;
        float ph = cp + pos[(tok & (LL-1))*KK + k];       // l = tok % L
        float za = aa[r] + bba;
        float amp = ((za > 20.f) ? za : log1pf(expf(za))) + 0.1f;
        float sn, cs;
        sincosf(ph, &sn, &cs);
        Pr [(size_t)tok*KK + k] = amp*cs;
        Pim[(size_t)tok*KK + k] = amp*sn;
    }
}

// ---------------------------------------------------------------------------
// Kernel B: causal phasor mixing.
//   retrieved[l,:] = sum_{l'<=l} c(l,l') V[l',:]
//   c(l,l') = sum_k Pr[l,k]Pr[l',k] + Pim[l,k]Pim[l',k]
// One block per (batch, 16-row tile); thread t owns output column d=t.
// Writes R = retrieved / sqrt((l+1)*K).
// ---------------------------------------------------------------------------
__global__ __launch_bounds__(256)
void mix_kernel(const float* __restrict__ V, const float* __restrict__ Pr,
                const float* __restrict__ Pim, float* __restrict__ R)
{
    __shared__ float prL[16][KK];      // reads wave-broadcast
    __shared__ float piL[16][KK];
    __shared__ float prC[64][KK+1];    // +1 pad: (j+k)&31 -> 2-way alias (free)
    __shared__ float piC[64][KK+1];
    __shared__ float cS[16][65];

    const int t    = threadIdx.x;
    const int b    = blockIdx.x >> 6;
    const int tile = blockIdx.x & 63;
    const int l0   = tile * 16;
    const size_t base = (size_t)b * LL;

    for (int i = t; i < 16*KK; i += 256){
        int r = i >> 6, k = i & 63;
        prL[r][k] = Pr [(base + l0 + r)*KK + k];
        piL[r][k] = Pim[(base + l0 + r)*KK + k];
    }

    float acc[16];
    #pragma unroll
    for (int r = 0; r < 16; r++) acc[r] = 0.f;

    const int lmax = l0 + 15;
    for (int c0 = 0; c0 <= lmax; c0 += 64){
        __syncthreads();   // also covers initial prL/piL load
        for (int i = t; i < 64*KK; i += 256){
            int j = i >> 6, k = i & 63;
            prC[j][k] = Pr [(base + c0 + j)*KK + k];  // c0+63 <= 1023 always
            piC[j][k] = Pim[(base + c0 + j)*KK + k];
        }
        __syncthreads();

        // score tile: thread (j=t&63, r0=t>>6) does rows r0, r0+4, r0+8, r0+12
        {
            int j = t & 63, r0 = t >> 6;
            #pragma unroll
            for (int rr = 0; rr < 4; rr++){
                int r = r0 + rr*4;
                float s = 0.f;
                #pragma unroll
                for (int k = 0; k < KK; k++)
                    s += prL[r][k]*prC[j][k] + piL[r][k]*piC[j][k];
                cS[r][j] = (c0 + j <= l0 + r) ? s : 0.f;   // causal mask
            }
        }
        __syncthreads();

        int jmax = min(64, lmax - c0 + 1);
        for (int j = 0; j < jmax; j++){
            float v = V[(base + c0 + j)*DD + t];   // coalesced
            #pragma unroll
            for (int r = 0; r < 16; r++)
                acc[r] += cS[r][j] * v;            // LDS broadcast
        }
    }

    #pragma unroll
    for (int r = 0; r < 16; r++){
        float nrm = rsqrtf((float)(l0 + r + 1) * (float)KK);
        R[(base + l0 + r)*DD + t] = acc[r] * nrm;
    }
}

// ---------------------------------------------------------------------------
// Kernel C: LayerNorm + Wo + residual. 16 tokens per block.
// ---------------------------------------------------------------------------
__global__ __launch_bounds__(256)
void out_kernel(const float* __restrict__ R, const float* __restrict__ x,
                const float* __restrict__ ln_g, const float* __restrict__ ln_b,
                const float* __restrict__ Wo, const float* __restrict__ bo,
                float* __restrict__ out)
{
    __shared__ float rn[16][DD];
    __shared__ float stats[16][2];
    const int t = threadIdx.x;
    const int tok0 = blockIdx.x * 16;

    for (int i = t; i < 16*DD; i += 256)
        rn[i>>8][i&255] = R[(size_t)(tok0 + (i>>8))*DD + (i&255)];
    __syncthreads();

    // per-row mean/var: wave w reduces rows w, w+4, w+8, w+12
    const int w = t >> 6, lane = t & 63;
    #pragma unroll
    for (int rr = 0; rr < 4; rr++){
        int r = w + rr*4;
        float s = 0.f, ss = 0.f;
        #pragma unroll
        for (int q = 0; q < 4; q++){
            float v = rn[r][lane*4 + q];
            s += v; ss += v*v;
        }
        for (int off = 32; off; off >>= 1){
            s  += __shfl_down(s, off);
            ss += __shfl_down(ss, off);
        }
        if (lane == 0){
            float mu = s * (1.0f/DD);
            float var = ss * (1.0f/DD) - mu*mu;
            stats[r][0] = mu;
            stats[r][1] = rsqrtf(var + 1e-5f);
        }
    }
    __syncthreads();

    float g = ln_g[t], bb = ln_b[t];
    float rnreg[16];
    #pragma unroll
    for (int r = 0; r < 16; r++)
        rnreg[r] = (rn[r][t] - stats[r][0]) * stats[r][1] * g + bb;
    __syncthreads();
    #pragma unroll
    for (int r = 0; r < 16; r++) rn[r][t] = rnreg[r];
    __syncthreads();

    float acc[16];
    #pragma unroll
    for (int r = 0; r < 16; r++) acc[r] = 0.f;
    for (int j = 0; j < DD; j++){
        float wo = Wo[j*DD + t];         // coalesced
        #pragma unroll
        for (int r = 0; r < 16; r++)
            acc[r] += rn[r][j] * wo;     // LDS broadcast
    }
    float bbo = bo[t];
    #pragma unroll
    for (int r = 0; r < 16; r++){
        size_t idx = (size_t)(tok0 + r)*DD + t;
        out[idx] = x[idx] + acc[r] + bbo;
    }
}

// ---------------------------------------------------------------------------
extern "C" void kernel_launch(void* const* d_in, const int* in_sizes, int n_in,
                              void* d_out, int out_size, void* d_ws, size_t ws_size,
                              hipStream_t stream) {
    const float* x    = (const float*)d_in[0];
    const float* pos  = (const float*)d_in[1];
    const float* W1   = (const float*)d_in[2];
    const float* b1   = (const float*)d_in[3];
    const float* W2   = (const float*)d_in[4];
    const float* b2_  = (const float*)d_in[5];
    const float* Wa   = (const float*)d_in[6];
    const float* ba   = (const float*)d_in[7];
    const float* Wv   = (const float*)d_in[8];
    const float* bv   = (const float*)d_in[9];
    const float* ln_g = (const float*)d_in[10];
    const float* ln_b = (const float*)d_in[11];
    const float* Wo   = (const float*)d_in[12];
    const float* bo   = (const float*)d_in[13];

    float* ws  = (float*)d_ws;
    float* V   = ws;                        // NN*DD
    float* Pr  = V   + (size_t)NN*DD;       // NN*KK
    float* Pim = Pr  + (size_t)NN*KK;       // NN*KK
    float* R   = Pim + (size_t)NN*KK;       // NN*DD

    encode_kernel<<<NN/16, 256, 0, stream>>>(x, pos, W1, b1, W2, b2_, Wa, ba,
                                             Wv, bv, V, Pr, Pim);
    mix_kernel<<<BB*(LL/16), 256, 0, stream>>>(V, Pr, Pim, R);
    out_kernel<<<NN/16, 256, 0, stream>>>(R, x, ln_g, ln_b, Wo, bo,
                                          (float*)d_out);
}

// Round 3
// 255.818 us; speedup vs baseline: 1.6525x; 1.6525x over previous
//
#include <hip/hip_runtime.h>
#include <math.h>

#define BB 4
#define LL 1024
#define DD 256
#define KK 64
#define NN (BB*LL)   // 4096 tokens

// ---------------------------------------------------------------------------
// Kernel A: per-token encoder. 16 tokens per block, 512 threads (8 waves).
//   h  = gelu(x@W1+b1)  (exact)     cp = tanh(h@W2+b2)*pi
//   amp= softplus(x@Wa+ba)+0.1      phase = pos_phases[l] + cp
//   Pr = amp*cos(phase), Pim = amp*sin(phase),  V = x@Wv+bv
// Phase 1 (D-wide): thread (half=t>>8, col=t&255) owns 8 rows x column col.
// Phase 2 (K-wide): wave w (t>>6) owns rows 2w,2w+1; lane = k.
// ---------------------------------------------------------------------------
__global__ __launch_bounds__(512)
void encode_kernel(const float* __restrict__ x, const float* __restrict__ pos,
                   const float* __restrict__ W1, const float* __restrict__ b1,
                   const float* __restrict__ W2, const float* __restrict__ b2,
                   const float* __restrict__ Wa, const float* __restrict__ ba,
                   const float* __restrict__ Wv, const float* __restrict__ bv,
                   float* __restrict__ Vout, float* __restrict__ Pr,
                   float* __restrict__ Pim)
{
    __shared__ float xs[16][DD];   // reads are broadcast; no pad needed
    __shared__ float hs[16][DD];
    const int t = threadIdx.x;
    const int tok0 = blockIdx.x * 16;

    for (int i = t; i < 16*DD; i += 512)
        xs[i>>8][i&255] = x[(size_t)tok0*DD + i];
    __syncthreads();

    const int col  = t & 255;
    const int r0   = (t >> 8) * 8;          // 0 or 8

    float acc1[8], acc2[8];
    #pragma unroll
    for (int r = 0; r < 8; r++){ acc1[r]=0.f; acc2[r]=0.f; }
    for (int j = 0; j < DD; j++){
        float w1 = W1[j*DD + col];          // coalesced across lanes
        float wv = Wv[j*DD + col];
        #pragma unroll
        for (int r = 0; r < 8; r++){
            float xv = xs[r0+r][j];         // LDS broadcast
            acc1[r] += xv*w1;
            acc2[r] += xv*wv;
        }
    }
    float bb1 = b1[col], bbv = bv[col];
    #pragma unroll
    for (int r = 0; r < 8; r++){
        float hpre = acc1[r] + bb1;
        hs[r0+r][col] = 0.5f*hpre*(1.0f + erff(hpre*0.70710678118f));
        Vout[(size_t)(tok0+r0+r)*DD + col] = acc2[r] + bbv;
    }
    __syncthreads();

    // K-wide outputs: wave w handles rows 2w, 2w+1; lane = k
    const int k = t & 63;
    const int w = t >> 6;                   // 0..7
    float a2[2], aa[2];
    #pragma unroll
    for (int r = 0; r < 2; r++){ a2[r]=0.f; aa[r]=0.f; }
    for (int j = 0; j < DD; j++){
        float w2 = W2[j*KK + k];
        float wa = Wa[j*KK + k];
        #pragma unroll
        for (int r = 0; r < 2; r++){
            a2[r] += hs[w*2+r][j]*w2;       // LDS broadcast within wave
            aa[r] += xs[w*2+r][j]*wa;
        }
    }
    float bb2 = b2[k], bba = ba[k];
    const float PI_ = 3.14159265358979323846f;
    #pragma unroll
    for (int r = 0; r < 2; r++){
        int tok = tok0 + w*2 + r;
        float cp = tanhf(a2[r] + bb2) * PI_;
        float ph = cp + pos[(tok & (LL-1))*KK + k];       // l = tok % L
        float za = aa[r] + bba;
        float amp = ((za > 20.f) ? za : log1pf(expf(za))) + 0.1f;
        float sn, cs;
        sincosf(ph, &sn, &cs);
        Pr [(size_t)tok*KK + k] = amp*cs;
        Pim[(size_t)tok*KK + k] = amp*sn;
    }
}

// ---------------------------------------------------------------------------
// Kernel B: causal phasor mixing, column-split for load balance.
//   retrieved[l,:] = sum_{l'<=l} c(l,l') V[l',:],
//   c(l,l') = sum_k Pr[l,k]Pr[l',k] + Pim[l,k]Pim[l',k]
// Grid: x = (b * 64 row-tiles), y = col-chunk (0..3, 256 cols each).
// Each block accumulates its partial into R via atomicAdd (R pre-zeroed).
// Normalization /sqrt((l+1)K) is applied later in out_kernel.
// ---------------------------------------------------------------------------
__global__ __launch_bounds__(256)
void mix_kernel(const float* __restrict__ V, const float* __restrict__ Pr,
                const float* __restrict__ Pim, float* __restrict__ R)
{
    const int t    = threadIdx.x;
    const int b    = blockIdx.x >> 6;
    const int tile = blockIdx.x & 63;
    const int l0   = tile * 16;
    const int lmax = l0 + 15;
    const int cs   = blockIdx.y * 256;
    if (cs > lmax) return;                 // no causal columns in this chunk
    const size_t base = (size_t)b * LL;

    __shared__ float prL[16][KK];          // reads broadcast
    __shared__ float piL[16][KK];
    __shared__ float prC[64][KK+1];        // pad: (j+k)&31 -> 2-way alias (free)
    __shared__ float piC[64][KK+1];
    __shared__ float cS[16][65];

    for (int i = t; i < 16*KK; i += 256){
        int r = i >> 6, k = i & 63;
        prL[r][k] = Pr [(base + l0 + r)*KK + k];
        piL[r][k] = Pim[(base + l0 + r)*KK + k];
    }

    float acc[16];
    #pragma unroll
    for (int r = 0; r < 16; r++) acc[r] = 0.f;

    const int ce = min(cs + 255, lmax);
    for (int c0 = cs; c0 <= ce; c0 += 64){
        __syncthreads();   // also covers initial prL/piL load
        for (int i = t; i < 64*KK; i += 256){
            int j = i >> 6, k = i & 63;
            prC[j][k] = Pr [(base + c0 + j)*KK + k];  // c0+63 <= 1023 always
            piC[j][k] = Pim[(base + c0 + j)*KK + k];
        }
        __syncthreads();

        // score tile: thread (j=t&63, r0=t>>6) does rows r0, r0+4, r0+8, r0+12
        {
            int j = t & 63, rb = t >> 6;
            #pragma unroll
            for (int rr = 0; rr < 4; rr++){
                int r = rb + rr*4;
                float s = 0.f;
                #pragma unroll 16          // cap unroll: keep VGPR < 256
                for (int k = 0; k < KK; k++)
                    s += prL[r][k]*prC[j][k] + piL[r][k]*piC[j][k];
                cS[r][j] = (c0 + j <= l0 + r) ? s : 0.f;   // causal mask
            }
        }
        __syncthreads();

        int jmax = min(64, lmax - c0 + 1);
        for (int j = 0; j < jmax; j++){
            float v = V[(base + c0 + j)*DD + t];   // coalesced
            #pragma unroll
            for (int r = 0; r < 16; r++)
                acc[r] += cS[r][j] * v;            // LDS broadcast
        }
    }

    #pragma unroll
    for (int r = 0; r < 16; r++)
        atomicAdd(&R[(base + l0 + r)*DD + t], acc[r]);
}

// ---------------------------------------------------------------------------
// Kernel C: norm + LayerNorm + Wo + residual. 16 tokens, 512 threads.
// ---------------------------------------------------------------------------
__global__ __launch_bounds__(512)
void out_kernel(const float* __restrict__ R, const float* __restrict__ x,
                const float* __restrict__ ln_g, const float* __restrict__ ln_b,
                const float* __restrict__ Wo, const float* __restrict__ bo,
                float* __restrict__ out)
{
    __shared__ float rn[16][DD];
    __shared__ float stats[16][2];
    const int t = threadIdx.x;
    const int tok0 = blockIdx.x * 16;

    for (int i = t; i < 16*DD; i += 512){
        int r = i >> 8;
        int l = (tok0 + r) & (LL-1);
        float nrm = rsqrtf((float)(l + 1) * (float)KK);
        rn[r][i&255] = R[(size_t)tok0*DD + i] * nrm;
    }
    __syncthreads();

    // per-row mean/var: wave w (0..7) reduces rows 2w, 2w+1
    const int w = t >> 6, lane = t & 63;
    #pragma unroll
    for (int rr = 0; rr < 2; rr++){
        int r = w*2 + rr;
        float s = 0.f, ss = 0.f;
        #pragma unroll
        for (int q = 0; q < 4; q++){
            float v = rn[r][q*64 + lane];   // stride-64: 2-way alias, free
            s += v; ss += v*v;
        }
        for (int off = 32; off; off >>= 1){
            s  += __shfl_down(s, off);
            ss += __shfl_down(ss, off);
        }
        if (lane == 0){
            float mu = s * (1.0f/DD);
            float var = ss * (1.0f/DD) - mu*mu;
            stats[r][0] = mu;
            stats[r][1] = rsqrtf(var + 1e-5f);
        }
    }
    __syncthreads();

    const int col = t & 255;
    const int r0  = (t >> 8) * 8;
    float g = ln_g[col], bb = ln_b[col];
    float v8[8];
    #pragma unroll
    for (int r = 0; r < 8; r++)
        v8[r] = (rn[r0+r][col] - stats[r0+r][0]) * stats[r0+r][1] * g + bb;
    __syncthreads();
    #pragma unroll
    for (int r = 0; r < 8; r++) rn[r0+r][col] = v8[r];
    __syncthreads();

    float acc[8];
    #pragma unroll
    for (int r = 0; r < 8; r++) acc[r] = 0.f;
    for (int j = 0; j < DD; j++){
        float wo = Wo[j*DD + col];          // coalesced
        #pragma unroll
        for (int r = 0; r < 8; r++)
            acc[r] += rn[r0+r][j] * wo;     // LDS broadcast
    }
    float bbo = bo[col];
    #pragma unroll
    for (int r = 0; r < 8; r++){
        size_t idx = (size_t)(tok0 + r0 + r)*DD + col;
        out[idx] = x[idx] + acc[r] + bbo;
    }
}

// ---------------------------------------------------------------------------
extern "C" void kernel_launch(void* const* d_in, const int* in_sizes, int n_in,
                              void* d_out, int out_size, void* d_ws, size_t ws_size,
                              hipStream_t stream) {
    const float* x    = (const float*)d_in[0];
    const float* pos  = (const float*)d_in[1];
    const float* W1   = (const float*)d_in[2];
    const float* b1   = (const float*)d_in[3];
    const float* W2   = (const float*)d_in[4];
    const float* b2_  = (const float*)d_in[5];
    const float* Wa   = (const float*)d_in[6];
    const float* ba   = (const float*)d_in[7];
    const float* Wv   = (const float*)d_in[8];
    const float* bv   = (const float*)d_in[9];
    const float* ln_g = (const float*)d_in[10];
    const float* ln_b = (const float*)d_in[11];
    const float* Wo   = (const float*)d_in[12];
    const float* bo   = (const float*)d_in[13];

    float* ws  = (float*)d_ws;
    float* V   = ws;                        // NN*DD
    float* Pr  = V   + (size_t)NN*DD;       // NN*KK
    float* Pim = Pr  + (size_t)NN*KK;       // NN*KK
    float* R   = Pim + (size_t)NN*KK;       // NN*DD

    hipMemsetAsync(R, 0, (size_t)NN*DD*sizeof(float), stream);

    encode_kernel<<<NN/16, 512, 0, stream>>>(x, pos, W1, b1, W2, b2_, Wa, ba,
                                             Wv, bv, V, Pr, Pim);
    dim3 mixgrid(BB*(LL/16), 4);
    mix_kernel<<<mixgrid, 256, 0, stream>>>(V, Pr, Pim, R);
    out_kernel<<<NN/16, 512, 0, stream>>>(R, x, ln_g, ln_b, Wo, bo,
                                          (float*)d_out);
}

// Round 4
// 183.426 us; speedup vs baseline: 2.3047x; 1.3947x over previous
//
#include <hip/hip_runtime.h>
#include <hip/hip_bf16.h>
#include <math.h>

#define BB 4
#define LL 1024
#define DD 256
#define KK 64
#define NN (BB*LL)   // 4096 tokens

typedef __attribute__((ext_vector_type(8))) short short8;
typedef __attribute__((ext_vector_type(4))) float f32x4;

__device__ __forceinline__ short f2bs(float f){
    union { __hip_bfloat16 h; short s; } u;
    u.h = __float2bfloat16(f);
    return u.s;
}

// ---------------------------------------------------------------------------
// Kernel A: per-token encoder. 16 tokens per block, 512 threads (8 waves).
// Emits bf16 Pb[tok][128] = [amp*cos | amp*sin]  and bf16 Vb[tok][256].
// Phase 1 register tile: thread owns 4 rows x 2 cols (FMA-bound j-loop).
// ---------------------------------------------------------------------------
__global__ __launch_bounds__(512)
void encode_kernel(const float* __restrict__ x, const float* __restrict__ pos,
                   const float* __restrict__ W1, const float* __restrict__ b1,
                   const float* __restrict__ W2, const float* __restrict__ b2,
                   const float* __restrict__ Wa, const float* __restrict__ ba,
                   const float* __restrict__ Wv, const float* __restrict__ bv,
                   short* __restrict__ Pb, short* __restrict__ Vb)
{
    __shared__ float xs[16][DD];
    __shared__ float hs[16][DD];
    const int t = threadIdx.x;
    const int tok0 = blockIdx.x * 16;

    for (int i = t; i < 16*DD; i += 512)
        xs[i>>8][i&255] = x[(size_t)tok0*DD + i];
    __syncthreads();

    // ---- phase 1: x@[W1|Wv], gelu -> hs, V -> Vb (bf16) ----
    const int rg = t >> 7;          // 0..3 -> rows rg*4 .. rg*4+3
    const int c0 = (t & 127) * 2;   // column pair

    float a1x[4]={0,0,0,0}, a1y[4]={0,0,0,0};
    float avx[4]={0,0,0,0}, avy[4]={0,0,0,0};
    for (int j = 0; j < DD; j += 4){
        float2 w1a = *(const float2*)&W1[(j+0)*DD + c0];
        float2 w1b = *(const float2*)&W1[(j+1)*DD + c0];
        float2 w1c = *(const float2*)&W1[(j+2)*DD + c0];
        float2 w1d = *(const float2*)&W1[(j+3)*DD + c0];
        float2 wva = *(const float2*)&Wv[(j+0)*DD + c0];
        float2 wvb = *(const float2*)&Wv[(j+1)*DD + c0];
        float2 wvc = *(const float2*)&Wv[(j+2)*DD + c0];
        float2 wvd = *(const float2*)&Wv[(j+3)*DD + c0];
        #pragma unroll
        for (int r = 0; r < 4; r++){
            float4 xv = *(const float4*)&xs[rg*4+r][j];   // wave-broadcast
            a1x[r] += xv.x*w1a.x + xv.y*w1b.x + xv.z*w1c.x + xv.w*w1d.x;
            a1y[r] += xv.x*w1a.y + xv.y*w1b.y + xv.z*w1c.y + xv.w*w1d.y;
            avx[r] += xv.x*wva.x + xv.y*wvb.x + xv.z*wvc.x + xv.w*wvd.x;
            avy[r] += xv.x*wva.y + xv.y*wvb.y + xv.z*wvc.y + xv.w*wvd.y;
        }
    }
    float b1x = b1[c0], b1y = b1[c0+1], bvx = bv[c0], bvy = bv[c0+1];
    #pragma unroll
    for (int r = 0; r < 4; r++){
        int row = rg*4 + r;
        float hx = a1x[r] + b1x, hy = a1y[r] + b1y;
        hs[row][c0]   = 0.5f*hx*(1.0f + erff(hx*0.70710678118f));
        hs[row][c0+1] = 0.5f*hy*(1.0f + erff(hy*0.70710678118f));
        Vb[(size_t)(tok0+row)*DD + c0]     = f2bs(avx[r] + bvx);
        Vb[(size_t)(tok0+row)*DD + c0 + 1] = f2bs(avy[r] + bvy);
    }
    __syncthreads();

    // ---- phase 2: tanh(h@W2)*pi, softplus(x@Wa)+0.1 -> Pb (bf16) ----
    const int k  = t & 63;
    const int w2 = t >> 6;          // 0..7 -> rows 2w2, 2w2+1
    float p2r[2] = {0,0}, par[2] = {0,0};
    for (int j = 0; j < DD; j += 4){
        float4 h0 = *(const float4*)&hs[w2*2+0][j];
        float4 h1 = *(const float4*)&hs[w2*2+1][j];
        float4 x0 = *(const float4*)&xs[w2*2+0][j];
        float4 x1 = *(const float4*)&xs[w2*2+1][j];
        float w2a = W2[(j+0)*KK+k], w2b = W2[(j+1)*KK+k];
        float w2c = W2[(j+2)*KK+k], w2d = W2[(j+3)*KK+k];
        float waa = Wa[(j+0)*KK+k], wab = Wa[(j+1)*KK+k];
        float wac = Wa[(j+2)*KK+k], wad = Wa[(j+3)*KK+k];
        p2r[0] += h0.x*w2a + h0.y*w2b + h0.z*w2c + h0.w*w2d;
        p2r[1] += h1.x*w2a + h1.y*w2b + h1.z*w2c + h1.w*w2d;
        par[0] += x0.x*waa + x0.y*wab + x0.z*wac + x0.w*wad;
        par[1] += x1.x*waa + x1.y*wab + x1.z*wac + x1.w*wad;
    }
    float bb2 = b2[k], bba = ba[k];
    const float PI_ = 3.14159265358979323846f;
    #pragma unroll
    for (int r = 0; r < 2; r++){
        int tok = tok0 + w2*2 + r;
        float cp = tanhf(p2r[r] + bb2) * PI_;
        float ph = cp + pos[(tok & (LL-1))*KK + k];
        float za = par[r] + bba;
        float amp = ((za > 20.f) ? za : log1pf(expf(za))) + 0.1f;
        float sn, cs;
        sincosf(ph, &sn, &cs);
        Pb[(size_t)tok*128 + k]      = f2bs(amp*cs);
        Pb[(size_t)tok*128 + 64 + k] = f2bs(amp*sn);
    }
}

// ---------------------------------------------------------------------------
// Kernel T: Vb[b*1024+l][d] (bf16) -> Vt[b*256+d][l] (bf16).
// One thread per 8-element output run; strided L2 reads, coalesced b128 write.
// ---------------------------------------------------------------------------
__global__ __launch_bounds__(256)
void transpose_v(const short* __restrict__ Vb, short* __restrict__ Vt)
{
    int o  = blockIdx.x * 256 + threadIdx.x;   // 0 .. 131071
    int b  = o >> 15;
    int d  = (o >> 7) & 255;
    int l0 = (o & 127) << 3;
    const short* src = Vb + ((size_t)b*1024 + l0)*DD + d;
    short8 v;
    #pragma unroll
    for (int i = 0; i < 8; i++) v[i] = src[(size_t)i*DD];
    *(short8*)(Vt + (((size_t)b*256 + d) << 10) + l0) = v;
}

// ---------------------------------------------------------------------------
// Kernel B: causal phasor mixing via MFMA (flash-attention pattern).
//   S(16x64) = P_L(16x128) @ P_C(64x128)^T   [4 n-subtiles x 4 k-steps]
//   mask causally, bf16 via per-wave LDS (C-layout -> A-layout round trip)
//   O(16x256) += S(16x64) @ V(64x256)        [16 n-subtiles x 2 k-steps]
// Block: 256 thr = 4 waves; wave w owns M-rows l0+16w..+15. No barriers.
// Grid: x = b*16 tiles-of-64-rows, y = 256-col chunk (load balance).
// P/V frags load directly from global (L2-resident). R accumulated fp32 atomics.
// MFMA layouts (verified, m89/m120): A[m=lane&15][k=quad*8+j];
// B[n=lane&15][k=quad*8+j]; C/D: col=lane&15, row=quad*4+reg.
// ---------------------------------------------------------------------------
__global__ __launch_bounds__(256)
void mix_kernel(const short* __restrict__ Pb, const short* __restrict__ Vt,
                float* __restrict__ R)
{
    const int t    = threadIdx.x;
    const int bb   = blockIdx.x >> 4;
    const int T    = blockIdx.x & 15;
    const int l0   = T * 64;
    const int cs   = blockIdx.y * 256;
    const int w    = t >> 6;
    const int lane = t & 63;
    const int m16  = lane & 15;
    const int quad = lane >> 4;
    const int mrow0 = l0 + w*16;
    const int lmaxw = mrow0 + 15;
    if (cs > lmaxw) return;            // wave-uniform early exit

    __shared__ __align__(16) short sS[4][16][72];   // per-wave, 72: pad->2-way

    f32x4 accO[16];
    #pragma unroll
    for (int i = 0; i < 16; i++) accO[i] = (f32x4){0.f,0.f,0.f,0.f};

    const short* PbB = Pb + (size_t)bb * 1024 * 128;
    const short* VtB = Vt + (size_t)bb * 256 * 1024;

    // A-frags of S (query rows): constant across c-iterations
    short8 aP[4];
    {
        const short* ar = PbB + (size_t)(mrow0 + m16) * 128 + quad*8;
        #pragma unroll
        for (int kk = 0; kk < 4; kk++) aP[kk] = *(const short8*)(ar + kk*32);
    }

    const int cend = min(cs + 192, lmaxw);
    for (int c0 = cs; c0 <= cend; c0 += 64){
        // ---- S = P_L @ P_C^T ----
        f32x4 accS[4];
        #pragma unroll
        for (int i = 0; i < 4; i++) accS[i] = (f32x4){0.f,0.f,0.f,0.f};
        #pragma unroll
        for (int ns = 0; ns < 4; ns++){
            const short* br = PbB + (size_t)(c0 + ns*16 + m16) * 128 + quad*8;
            #pragma unroll
            for (int kk = 0; kk < 4; kk++){
                short8 bP = *(const short8*)(br + kk*32);
                accS[ns] = __builtin_amdgcn_mfma_f32_16x16x32_bf16(
                               aP[kk], bP, accS[ns], 0, 0, 0);
            }
        }
        // ---- causal mask + C-layout -> A-layout (bf16) via per-wave LDS ----
        #pragma unroll
        for (int ns = 0; ns < 4; ns++){
            int ccol = c0 + ns*16 + m16;           // col = lane&15
            #pragma unroll
            for (int r2 = 0; r2 < 4; r2++){
                int rrow = mrow0 + quad*4 + r2;    // row = quad*4+reg
                float v = (ccol <= rrow) ? accS[ns][r2] : 0.f;
                sS[w][quad*4 + r2][ns*16 + m16] = f2bs(v);
            }
        }
        short8 aS0 = *(const short8*)&sS[w][m16][quad*8];        // k 0..31
        short8 aS1 = *(const short8*)&sS[w][m16][32 + quad*8];   // k 32..63
        // ---- O += S @ V ----
        #pragma unroll
        for (int ns = 0; ns < 16; ns++){
            const short* vr = VtB + (size_t)(ns*16 + m16) * 1024 + c0 + quad*8;
            short8 b0 = *(const short8*)(vr);
            short8 b1v = *(const short8*)(vr + 32);
            accO[ns] = __builtin_amdgcn_mfma_f32_16x16x32_bf16(
                           aS0, b0, accO[ns], 0, 0, 0);
            accO[ns] = __builtin_amdgcn_mfma_f32_16x16x32_bf16(
                           aS1, b1v, accO[ns], 0, 0, 0);
        }
    }

    float* Rb = R + (size_t)bb * 1024 * 256;
    #pragma unroll
    for (int ns = 0; ns < 16; ns++){
        #pragma unroll
        for (int r2 = 0; r2 < 4; r2++){
            int rrow = mrow0 + quad*4 + r2;
            atomicAdd(&Rb[(size_t)rrow*256 + ns*16 + m16], accO[ns][r2]);
        }
    }
}

// ---------------------------------------------------------------------------
// Kernel C: /sqrt((l+1)K) + LayerNorm + Wo + residual. 16 tokens, 512 thr.
// ---------------------------------------------------------------------------
__global__ __launch_bounds__(512)
void out_kernel(const float* __restrict__ R, const float* __restrict__ x,
                const float* __restrict__ ln_g, const float* __restrict__ ln_b,
                const float* __restrict__ Wo, const float* __restrict__ bo,
                float* __restrict__ out)
{
    __shared__ float rn[16][DD];
    __shared__ float stats[16][2];
    const int t = threadIdx.x;
    const int tok0 = blockIdx.x * 16;

    for (int i = t; i < 16*DD; i += 512){
        int r = i >> 8;
        int l = (tok0 + r) & (LL-1);
        float nrm = rsqrtf((float)(l + 1) * (float)KK);
        rn[r][i&255] = R[(size_t)tok0*DD + i] * nrm;
    }
    __syncthreads();

    // per-row mean/var: wave w (0..7) reduces rows 2w, 2w+1
    const int w = t >> 6, lane = t & 63;
    #pragma unroll
    for (int rr = 0; rr < 2; rr++){
        int r = w*2 + rr;
        float s = 0.f, ss = 0.f;
        #pragma unroll
        for (int q = 0; q < 4; q++){
            float v = rn[r][q*64 + lane];   // stride-64: 2-way alias, free
            s += v; ss += v*v;
        }
        for (int off = 32; off; off >>= 1){
            s  += __shfl_down(s, off);
            ss += __shfl_down(ss, off);
        }
        if (lane == 0){
            float mu = s * (1.0f/DD);
            float var = ss * (1.0f/DD) - mu*mu;
            stats[r][0] = mu;
            stats[r][1] = rsqrtf(var + 1e-5f);
        }
    }
    __syncthreads();

    {   // normalize in place (col-per-thread ownership)
        const int col = t & 255;
        const int r0  = (t >> 8) * 8;
        float g = ln_g[col], bb = ln_b[col];
        float v8[8];
        #pragma unroll
        for (int r = 0; r < 8; r++)
            v8[r] = (rn[r0+r][col] - stats[r0+r][0]) * stats[r0+r][1] * g + bb;
        __syncthreads();
        #pragma unroll
        for (int r = 0; r < 8; r++) rn[r0+r][col] = v8[r];
        __syncthreads();
    }

    // GEMM: thread owns 4 rows x 2 cols (FMA-bound j-loop)
    const int rg = t >> 7;          // 0..3
    const int c0 = (t & 127) * 2;
    float ax[4] = {0,0,0,0}, ay[4] = {0,0,0,0};
    for (int j = 0; j < DD; j += 4){
        float2 woa = *(const float2*)&Wo[(j+0)*DD + c0];
        float2 wob = *(const float2*)&Wo[(j+1)*DD + c0];
        float2 woc = *(const float2*)&Wo[(j+2)*DD + c0];
        float2 wod = *(const float2*)&Wo[(j+3)*DD + c0];
        #pragma unroll
        for (int r = 0; r < 4; r++){
            float4 rv = *(const float4*)&rn[rg*4+r][j];   // wave-broadcast
            ax[r] += rv.x*woa.x + rv.y*wob.x + rv.z*woc.x + rv.w*wod.x;
            ay[r] += rv.x*woa.y + rv.y*wob.y + rv.z*woc.y + rv.w*wod.y;
        }
    }
    float box = bo[c0], boy = bo[c0+1];
    #pragma unroll
    for (int r = 0; r < 4; r++){
        size_t idx = (size_t)(tok0 + rg*4 + r)*DD + c0;
        float2 xr = *(const float2*)&x[idx];
        float2 o;
        o.x = xr.x + ax[r] + box;
        o.y = xr.y + ay[r] + boy;
        *(float2*)&out[idx] = o;
    }
}

// ---------------------------------------------------------------------------
extern "C" void kernel_launch(void* const* d_in, const int* in_sizes, int n_in,
                              void* d_out, int out_size, void* d_ws, size_t ws_size,
                              hipStream_t stream) {
    const float* x    = (const float*)d_in[0];
    const float* pos  = (const float*)d_in[1];
    const float* W1   = (const float*)d_in[2];
    const float* b1   = (const float*)d_in[3];
    const float* W2   = (const float*)d_in[4];
    const float* b2_  = (const float*)d_in[5];
    const float* Wa   = (const float*)d_in[6];
    const float* ba   = (const float*)d_in[7];
    const float* Wv   = (const float*)d_in[8];
    const float* bv   = (const float*)d_in[9];
    const float* ln_g = (const float*)d_in[10];
    const float* ln_b = (const float*)d_in[11];
    const float* Wo   = (const float*)d_in[12];
    const float* bo   = (const float*)d_in[13];

    float* R  = (float*)d_ws;                       // NN*DD fp32
    short* Pb = (short*)(R + (size_t)NN*DD);        // NN*128 bf16
    short* Vb = Pb + (size_t)NN*128;                // NN*256 bf16
    short* Vt = Vb + (size_t)NN*256;                // NN*256 bf16 (transposed)

    hipMemsetAsync(R, 0, (size_t)NN*DD*sizeof(float), stream);

    encode_kernel<<<NN/16, 512, 0, stream>>>(x, pos, W1, b1, W2, b2_, Wa, ba,
                                             Wv, bv, Pb, Vb);
    transpose_v<<<512, 256, 0, stream>>>(Vb, Vt);
    dim3 mixgrid(BB*16, 4);
    mix_kernel<<<mixgrid, 256, 0, stream>>>(Pb, Vt, R);
    out_kernel<<<NN/16, 512, 0, stream>>>(R, x, ln_g, ln_b, Wo, bo,
                                          (float*)d_out);
}

// Round 5
// 150.357 us; speedup vs baseline: 2.8115x; 1.2199x over previous
//
#include <hip/hip_runtime.h>
#include <hip/hip_bf16.h>
#include <math.h>

#define BB 4
#define LL 1024
#define DD 256
#define KK 64
#define NN (BB*LL)   // 4096 tokens

typedef __attribute__((ext_vector_type(8))) short short8;
typedef __attribute__((ext_vector_type(4))) float f32x4;

__device__ __forceinline__ short f2bs(float f){
    union { __hip_bfloat16 h; short s; } u;
    u.h = __float2bfloat16(f);
    return u.s;
}

// ---------------------------------------------------------------------------
// Kernel P: weight transpose + bf16 cast, and x -> bf16.
//   W1t/Wvt/Wot[n][k] = bf16(W[k][n])  (256x256);  Wat/W2t (64x256)
//   xb[i] = bf16(x[i])
// Flat grid covering all 1,277,952 outputs.
// ---------------------------------------------------------------------------
__global__ __launch_bounds__(256)
void prep_kernel(const float* __restrict__ x,
                 const float* __restrict__ W1, const float* __restrict__ Wv,
                 const float* __restrict__ Wo, const float* __restrict__ W2,
                 const float* __restrict__ Wa,
                 short* __restrict__ xb,
                 short* __restrict__ W1t, short* __restrict__ Wvt,
                 short* __restrict__ Wot, short* __restrict__ W2t,
                 short* __restrict__ Wat)
{
    int o = blockIdx.x * 256 + threadIdx.x;
    if (o < NN*DD){                       // xb
        xb[o] = f2bs(x[o]);
        return;
    }
    o -= NN*DD;
    if (o < 3*DD*DD){                     // 256x256 transposes
        int m = o / (DD*DD);              // which matrix
        int e = o - m*DD*DD;
        int n = e >> 8, k = e & 255;
        const float* src = (m==0) ? W1 : (m==1) ? Wv : Wo;
        short* dst = (m==0) ? W1t : (m==1) ? Wvt : Wot;
        dst[n*DD + k] = f2bs(src[k*DD + n]);
        return;
    }
    o -= 3*DD*DD;                         // 64x256 transposes (2x16384)
    int m = o >> 14;
    int e = o & 16383;
    int n = e >> 8, k = e & 255;
    const float* src = (m==0) ? W2 : Wa;
    short* dst = (m==0) ? W2t : Wat;
    dst[n*DD + k] = f2bs(src[k*KK + n]);
}

// ---------------------------------------------------------------------------
// Kernel A: encoder via MFMA. 16 tokens/block, 256 thr = 4 waves.
//   GEMM1: H = gelu(X@W1+b1) -> LDS bf16;  V = X@Wv+bv -> Vb bf16
//   GEMM2: tanh(H@W2+b2)*pi, softplus(X@Wa+ba)+0.1 -> Pb bf16
// Wave w owns output cols [64w,64w+64) of GEMM1 and col-16 chunk w of GEMM2.
// MFMA layouts (verified): A[m=lane&15][k=quad*8+j]; B[n=lane&15][k=quad*8+j];
// C/D: col=lane&15, row=quad*4+reg.
// ---------------------------------------------------------------------------
__global__ __launch_bounds__(256)
void encode_kernel(const short* __restrict__ xb, const float* __restrict__ pos,
                   const short* __restrict__ W1t, const short* __restrict__ Wvt,
                   const short* __restrict__ W2t, const short* __restrict__ Wat,
                   const float* __restrict__ b1, const float* __restrict__ bv,
                   const float* __restrict__ b2, const float* __restrict__ ba,
                   short* __restrict__ Pb, short* __restrict__ Vb)
{
    const int t = threadIdx.x;
    const int w = t >> 6, lane = t & 63;
    const int m16 = lane & 15, quad = lane >> 4;
    const int tok0 = blockIdx.x * 16;

    __shared__ __align__(16) short hsb[16][264];   // +8 pad, 16B-aligned rows

    // A-frags: X rows tok0..tok0+15, all K=256 (8 k-steps)
    short8 aX[8];
    {
        const short* xr = xb + (size_t)(tok0 + m16)*DD + quad*8;
        #pragma unroll
        for (int kk = 0; kk < 8; kk++) aX[kk] = *(const short8*)(xr + kk*32);
    }

    // ---- GEMM1: accH = X@W1, accV = X@Wv (cols w*64 + ns*16 + m16) ----
    f32x4 accH[4], accV[4];
    #pragma unroll
    for (int i = 0; i < 4; i++){ accH[i] = (f32x4){0,0,0,0}; accV[i] = (f32x4){0,0,0,0}; }
    #pragma unroll
    for (int kk = 0; kk < 8; kk++){
        const short* p1 = W1t + (size_t)(w*64 + m16)*DD + kk*32 + quad*8;
        const short* pv = Wvt + (size_t)(w*64 + m16)*DD + kk*32 + quad*8;
        #pragma unroll
        for (int ns = 0; ns < 4; ns++){
            accH[ns] = __builtin_amdgcn_mfma_f32_16x16x32_bf16(
                           aX[kk], *(const short8*)(p1 + ns*16*DD), accH[ns], 0,0,0);
            accV[ns] = __builtin_amdgcn_mfma_f32_16x16x32_bf16(
                           aX[kk], *(const short8*)(pv + ns*16*DD), accV[ns], 0,0,0);
        }
    }
    // epilogue 1: gelu -> hsb (LDS), V -> Vb (global bf16)
    #pragma unroll
    for (int ns = 0; ns < 4; ns++){
        int col = w*64 + ns*16 + m16;
        float bb1 = b1[col], bbv = bv[col];
        #pragma unroll
        for (int r2 = 0; r2 < 4; r2++){
            int row = quad*4 + r2;
            float hx = accH[ns][r2] + bb1;
            hsb[row][col] = f2bs(0.5f*hx*(1.0f + erff(hx*0.70710678118f)));
            Vb[(size_t)(tok0+row)*DD + col] = f2bs(accV[ns][r2] + bbv);
        }
    }
    __syncthreads();

    // ---- GEMM2: accT = H@W2, accA = X@Wa (cols w*16 + m16) ----
    f32x4 accT = (f32x4){0,0,0,0}, accA = (f32x4){0,0,0,0};
    {
        const short* p2 = W2t + (size_t)(w*16 + m16)*DD + quad*8;
        const short* pa = Wat + (size_t)(w*16 + m16)*DD + quad*8;
        #pragma unroll
        for (int kk = 0; kk < 8; kk++){
            short8 aH = *(const short8*)&hsb[m16][kk*32 + quad*8];
            accT = __builtin_amdgcn_mfma_f32_16x16x32_bf16(
                       aH, *(const short8*)(p2 + kk*32), accT, 0,0,0);
            accA = __builtin_amdgcn_mfma_f32_16x16x32_bf16(
                       aX[kk], *(const short8*)(pa + kk*32), accA, 0,0,0);
        }
    }
    // epilogue 2: phases/amps -> Pb[tok][128] = [amp*cos | amp*sin]
    const int k = w*16 + m16;
    float bb2 = b2[k], bba = ba[k];
    const float PI_ = 3.14159265358979323846f;
    #pragma unroll
    for (int r2 = 0; r2 < 4; r2++){
        int tok = tok0 + quad*4 + r2;
        float cp = tanhf(accT[r2] + bb2) * PI_;
        float ph = cp + pos[(tok & (LL-1))*KK + k];
        float za = accA[r2] + bba;
        float amp = ((za > 20.f) ? za : log1pf(expf(za))) + 0.1f;
        float sn, cs;
        sincosf(ph, &sn, &cs);
        Pb[(size_t)tok*128 + k]      = f2bs(amp*cs);
        Pb[(size_t)tok*128 + 64 + k] = f2bs(amp*sn);
    }
}

// ---------------------------------------------------------------------------
// Kernel T: Vb[b*1024+l][d] (bf16) -> Vt[b*256+d][l] (bf16).
// ---------------------------------------------------------------------------
__global__ __launch_bounds__(256)
void transpose_v(const short* __restrict__ Vb, short* __restrict__ Vt)
{
    int o  = blockIdx.x * 256 + threadIdx.x;   // 0 .. 131071
    int b  = o >> 15;
    int d  = (o >> 7) & 255;
    int l0 = (o & 127) << 3;
    const short* src = Vb + ((size_t)b*1024 + l0)*DD + d;
    short8 v;
    #pragma unroll
    for (int i = 0; i < 8; i++) v[i] = src[(size_t)i*DD];
    *(short8*)(Vt + (((size_t)b*256 + d) << 10) + l0) = v;
}

// ---------------------------------------------------------------------------
// Kernel B: causal phasor mixing via MFMA (flash-attention pattern).
// Unchanged from round 4 (fell off the top-5; ~10-20 us).
// ---------------------------------------------------------------------------
__global__ __launch_bounds__(256)
void mix_kernel(const short* __restrict__ Pb, const short* __restrict__ Vt,
                float* __restrict__ R)
{
    const int t    = threadIdx.x;
    const int bb   = blockIdx.x >> 4;
    const int T    = blockIdx.x & 15;
    const int l0   = T * 64;
    const int cs   = blockIdx.y * 256;
    const int w    = t >> 6;
    const int lane = t & 63;
    const int m16  = lane & 15;
    const int quad = lane >> 4;
    const int mrow0 = l0 + w*16;
    const int lmaxw = mrow0 + 15;
    if (cs > lmaxw) return;            // wave-uniform early exit

    __shared__ __align__(16) short sS[4][16][72];   // per-wave, 72: pad->2-way

    f32x4 accO[16];
    #pragma unroll
    for (int i = 0; i < 16; i++) accO[i] = (f32x4){0.f,0.f,0.f,0.f};

    const short* PbB = Pb + (size_t)bb * 1024 * 128;
    const short* VtB = Vt + (size_t)bb * 256 * 1024;

    short8 aP[4];
    {
        const short* ar = PbB + (size_t)(mrow0 + m16) * 128 + quad*8;
        #pragma unroll
        for (int kk = 0; kk < 4; kk++) aP[kk] = *(const short8*)(ar + kk*32);
    }

    const int cend = min(cs + 192, lmaxw);
    for (int c0 = cs; c0 <= cend; c0 += 64){
        f32x4 accS[4];
        #pragma unroll
        for (int i = 0; i < 4; i++) accS[i] = (f32x4){0.f,0.f,0.f,0.f};
        #pragma unroll
        for (int ns = 0; ns < 4; ns++){
            const short* br = PbB + (size_t)(c0 + ns*16 + m16) * 128 + quad*8;
            #pragma unroll
            for (int kk = 0; kk < 4; kk++){
                short8 bP = *(const short8*)(br + kk*32);
                accS[ns] = __builtin_amdgcn_mfma_f32_16x16x32_bf16(
                               aP[kk], bP, accS[ns], 0, 0, 0);
            }
        }
        #pragma unroll
        for (int ns = 0; ns < 4; ns++){
            int ccol = c0 + ns*16 + m16;
            #pragma unroll
            for (int r2 = 0; r2 < 4; r2++){
                int rrow = mrow0 + quad*4 + r2;
                float v = (ccol <= rrow) ? accS[ns][r2] : 0.f;
                sS[w][quad*4 + r2][ns*16 + m16] = f2bs(v);
            }
        }
        short8 aS0 = *(const short8*)&sS[w][m16][quad*8];
        short8 aS1 = *(const short8*)&sS[w][m16][32 + quad*8];
        #pragma unroll
        for (int ns = 0; ns < 16; ns++){
            const short* vr = VtB + (size_t)(ns*16 + m16) * 1024 + c0 + quad*8;
            short8 b0 = *(const short8*)(vr);
            short8 b1v = *(const short8*)(vr + 32);
            accO[ns] = __builtin_amdgcn_mfma_f32_16x16x32_bf16(
                           aS0, b0, accO[ns], 0, 0, 0);
            accO[ns] = __builtin_amdgcn_mfma_f32_16x16x32_bf16(
                           aS1, b1v, accO[ns], 0, 0, 0);
        }
    }

    float* Rb = R + (size_t)bb * 1024 * 256;
    #pragma unroll
    for (int ns = 0; ns < 16; ns++){
        #pragma unroll
        for (int r2 = 0; r2 < 4; r2++){
            int rrow = mrow0 + quad*4 + r2;
            atomicAdd(&Rb[(size_t)rrow*256 + ns*16 + m16], accO[ns][r2]);
        }
    }
}

// ---------------------------------------------------------------------------
// Kernel C: /sqrt((l+1)K) + LayerNorm (fp32) + Wo via MFMA + residual.
// 16 tokens/block, 256 thr = 4 waves; wave w owns cols [64w, 64w+64).
// ---------------------------------------------------------------------------
__global__ __launch_bounds__(256)
void out_kernel(const float* __restrict__ R, const float* __restrict__ x,
                const float* __restrict__ ln_g, const float* __restrict__ ln_b,
                const short* __restrict__ Wot, const float* __restrict__ bo,
                float* __restrict__ out)
{
    const int t = threadIdx.x;
    const int w = t >> 6, lane = t & 63;
    const int m16 = lane & 15, quad = lane >> 4;
    const int tok0 = blockIdx.x * 16;

    __shared__ float rs[16][DD];
    __shared__ __align__(16) short rnb[16][264];
    __shared__ float stats[16][2];

    for (int i = t; i < 16*DD; i += 256){
        int r = i >> 8;
        int l = (tok0 + r) & (LL-1);
        rs[r][i&255] = R[(size_t)tok0*DD + i] * rsqrtf((float)(l+1) * (float)KK);
    }
    __syncthreads();

    // wave w reduces rows 4w..4w+3
    #pragma unroll
    for (int rr = 0; rr < 4; rr++){
        int r = w*4 + rr;
        float s = 0.f, ss = 0.f;
        #pragma unroll
        for (int q = 0; q < 4; q++){
            float v = rs[r][q*64 + lane];   // stride-64: 2-way alias, free
            s += v; ss += v*v;
        }
        for (int off = 32; off; off >>= 1){
            s  += __shfl_down(s, off);
            ss += __shfl_down(ss, off);
        }
        if (lane == 0){
            float mu = s * (1.0f/DD);
            float var = ss * (1.0f/DD) - mu*mu;
            stats[r][0] = mu;
            stats[r][1] = rsqrtf(var + 1e-5f);
        }
    }
    __syncthreads();

    for (int i = t; i < 16*DD; i += 256){
        int r = i >> 8, c = i & 255;
        rnb[r][c] = f2bs((rs[r][c] - stats[r][0]) * stats[r][1] * ln_g[c] + ln_b[c]);
    }
    __syncthreads();

    // GEMM: rn @ Wo, wave w -> cols w*64 + ns*16 + m16
    f32x4 acc[4];
    #pragma unroll
    for (int i = 0; i < 4; i++) acc[i] = (f32x4){0,0,0,0};
    #pragma unroll
    for (int kk = 0; kk < 8; kk++){
        short8 aR = *(const short8*)&rnb[m16][kk*32 + quad*8];
        const short* po = Wot + (size_t)(w*64 + m16)*DD + kk*32 + quad*8;
        #pragma unroll
        for (int ns = 0; ns < 4; ns++)
            acc[ns] = __builtin_amdgcn_mfma_f32_16x16x32_bf16(
                          aR, *(const short8*)(po + ns*16*DD), acc[ns], 0,0,0);
    }
    #pragma unroll
    for (int ns = 0; ns < 4; ns++){
        int col = w*64 + ns*16 + m16;
        float bbo = bo[col];
        #pragma unroll
        for (int r2 = 0; r2 < 4; r2++){
            size_t idx = (size_t)(tok0 + quad*4 + r2)*DD + col;
            out[idx] = x[idx] + acc[ns][r2] + bbo;
        }
    }
}

// ---------------------------------------------------------------------------
extern "C" void kernel_launch(void* const* d_in, const int* in_sizes, int n_in,
                              void* d_out, int out_size, void* d_ws, size_t ws_size,
                              hipStream_t stream) {
    const float* x    = (const float*)d_in[0];
    const float* pos  = (const float*)d_in[1];
    const float* W1   = (const float*)d_in[2];
    const float* b1   = (const float*)d_in[3];
    const float* W2   = (const float*)d_in[4];
    const float* b2_  = (const float*)d_in[5];
    const float* Wa   = (const float*)d_in[6];
    const float* ba   = (const float*)d_in[7];
    const float* Wv   = (const float*)d_in[8];
    const float* bv   = (const float*)d_in[9];
    const float* ln_g = (const float*)d_in[10];
    const float* ln_b = (const float*)d_in[11];
    const float* Wo   = (const float*)d_in[12];
    const float* bo   = (const float*)d_in[13];

    float* R   = (float*)d_ws;                      // NN*DD fp32 (4 MB)
    short* Pb  = (short*)(R + (size_t)NN*DD);       // NN*128 bf16 (1 MB)
    short* Vb  = Pb  + (size_t)NN*128;              // NN*256 bf16 (2 MB)
    short* Vt  = Vb  + (size_t)NN*256;              // NN*256 bf16 (2 MB)
    short* xb  = Vt  + (size_t)NN*256;              // NN*256 bf16 (2 MB)
    short* W1t = xb  + (size_t)NN*256;              // 64K
    short* Wvt = W1t + DD*DD;
    short* Wot = Wvt + DD*DD;
    short* W2t = Wot + DD*DD;
    short* Wat = W2t + KK*DD;                       // + 16K  (total ~11.4 MB)

    hipMemsetAsync(R, 0, (size_t)NN*DD*sizeof(float), stream);

    const int prep_n = NN*DD + 3*DD*DD + 2*KK*DD;   // 1,277,952
    prep_kernel<<<(prep_n + 255)/256, 256, 0, stream>>>(
        x, W1, Wv, Wo, W2, Wa, xb, W1t, Wvt, Wot, W2t, Wat);

    encode_kernel<<<NN/16, 256, 0, stream>>>(xb, pos, W1t, Wvt, W2t, Wat,
                                             b1, bv, b2_, ba, Pb, Vb);
    transpose_v<<<512, 256, 0, stream>>>(Vb, Vt);
    dim3 mixgrid(BB*16, 4);
    mix_kernel<<<mixgrid, 256, 0, stream>>>(Pb, Vt, R);
    out_kernel<<<NN/16, 256, 0, stream>>>(R, x, ln_g, ln_b, Wot, bo,
                                          (float*)d_out);
}